// Round 7
// baseline (235.716 us; speedup 1.0000x reference)
//
#include <hip/hip_runtime.h>
#include <hip/hip_bf16.h>

#define BATCH 4
#define SEQ   2048
#define DIN   1024
#define DOUT  1024
#define N3    3072
#define MTOT  (BATCH*SEQ)

typedef __hip_bfloat16 bf16;
typedef __attribute__((ext_vector_type(8))) short bf16x8;
typedef __attribute__((ext_vector_type(4))) float f32x4;

#define MFMA(a,b,c) __builtin_amdgcn_mfma_f32_16x16x32_bf16(a,b,c,0,0,0)

union pack4 { bf16 h[4]; uint2 u2; };
union pack8 { bf16 h[8]; bf16x8 v; };

// async 16B global->LDS (DMA, no VGPR round-trip)
__device__ __forceinline__ void gl16(const bf16* g, bf16* l)
{
    __builtin_amdgcn_global_load_lds(
        (const __attribute__((address_space(1))) void*)g,
        (__attribute__((address_space(3))) void*)l, 16, 0, 0);
}

// ---------------- fused conversions (+ RS zero-fill) ----------------

__global__ __launch_bounds__(256)
void k_prep(const float* __restrict__ x, const float* __restrict__ Wq,
            const float* __restrict__ Wk, const float* __restrict__ Wv,
            bf16* __restrict__ xb, bf16* __restrict__ Wt,
            float* __restrict__ RS)
{
    __shared__ bf16 t[64][68];
    const int bid = blockIdx.x;
    if (bid < 8192) {
        long i = ((long)bid * 256 + threadIdx.x) * 4;
        float4 v = *(const float4*)(x + i);
        pack4 o;
        o.h[0] = __float2bfloat16(v.x);
        o.h[1] = __float2bfloat16(v.y);
        o.h[2] = __float2bfloat16(v.z);
        o.h[3] = __float2bfloat16(v.w);
        *(uint2*)(xb + i) = o.u2;
        return;
    }
    if (bid >= 8960) {                         // RS zero-fill (8192 floats)
        int i = (bid - 8960) * 1024 + threadIdx.x * 4;
        *(float4*)(RS + i) = make_float4(0.f, 0.f, 0.f, 0.f);
        return;
    }
    const int idx = bid - 8192;                // 0..767
    const int mat = idx >> 8;
    const int rem = idx & 255;
    const int k0 = (rem >> 4) * 64, n0 = (rem & 15) * 64;
    const float* W = (mat == 0) ? Wq : ((mat == 1) ? Wk : Wv);
#pragma unroll
    for (int p = 0; p < 4; ++p) {
        int kr = p * 16 + (threadIdx.x >> 4);
        int c4 = (threadIdx.x & 15) * 4;
        float4 v = *(const float4*)&W[(long)(k0 + kr) * DOUT + n0 + c4];
        t[c4 + 0][kr] = __float2bfloat16(v.x);
        t[c4 + 1][kr] = __float2bfloat16(v.y);
        t[c4 + 2][kr] = __float2bfloat16(v.z);
        t[c4 + 3][kr] = __float2bfloat16(v.w);
    }
    __syncthreads();
    bf16* O = Wt + (long)mat * DIN * DOUT;
#pragma unroll
    for (int i = 0; i < 2; ++i) {
        int l = threadIdx.x + i * 256;
        int n = l >> 3, c8 = (l & 7) * 8;
        pack8 o;
#pragma unroll
        for (int j = 0; j < 8; ++j) o.h[j] = t[n][c8 + j];
        *(bf16x8*)&O[(long)(n0 + n) * DIN + k0 + c8] = o.v;
    }
}

// ---------------- shared GEMM core, BK=64 (round-0 verified) ----------------

__device__ __forceinline__ void gemm_core(
    const bf16* __restrict__ Ab, long lda,
    const bf16* __restrict__ Bb, long ldb,
    int nk, bf16* __restrict__ As, bf16* __restrict__ Bs,
    f32x4 acc[4][4])
{
    const int tid  = threadIdx.x;
    const int lane = tid & 63;
    const int wave = tid >> 6;
    const int wm = (wave >> 1) * 64;
    const int wn = (wave & 1) * 64;
    const int r  = lane & 15;
    const int qd = lane >> 4;

    const int row0 = tid >> 3;                    // 0..31
    const int c    = (tid & 7) ^ (row0 & 7);      // swizzled source chunk
    const long aoff = (long)row0 * lda + c * 8;
    const long boff = (long)row0 * ldb + c * 8;
    const long astep = 32 * lda, bstep = 32 * ldb;
    bf16* dA = &As[tid * 8];
    bf16* dB = &Bs[tid * 8];

    for (int kk = 0; kk < nk; ++kk) {
        const bf16* A = Ab + kk * 64 + aoff;
        const bf16* B = Bb + kk * 64 + boff;
#pragma unroll
        for (int i = 0; i < 4; ++i) {
            gl16(A + i * astep, dA + i * 2048);
            gl16(B + i * bstep, dB + i * 2048);
        }
        __syncthreads();                           // drains vmcnt
#pragma unroll
        for (int ks = 0; ks < 2; ++ks) {
            const int slot = ((ks * 4 + qd) ^ (r & 7)) * 8;
            bf16x8 af[4], bv[4];
#pragma unroll
            for (int mi = 0; mi < 4; ++mi)
                af[mi] = *(const bf16x8*)&As[(wm + mi * 16 + r) * 64 + slot];
#pragma unroll
            for (int ni = 0; ni < 4; ++ni)
                bv[ni] = *(const bf16x8*)&Bs[(wn + ni * 16 + r) * 64 + slot];
#pragma unroll
            for (int mi = 0; mi < 4; ++mi)
#pragma unroll
                for (int ni = 0; ni < 4; ++ni)
                    acc[mi][ni] = MFMA(af[mi], bv[ni], acc[mi][ni]);
        }
        __syncthreads();
    }
}

// ---------------- QKV projection (n-slab dispatches) ----------------
// Split into 3 launches of 8 n-tiles x 64 m-tiles (512 blocks = 2/CU each):
// (a) probe: each slab < any plausible scores/pv time -> top-5 reveals them;
// (b) each slab's B-panel is 2 MB -> L2-resident per XCD.

__global__ __launch_bounds__(256)
void k_gemm_qkv(const bf16* __restrict__ xb, const bf16* __restrict__ Wt,
                bf16* __restrict__ QK, bf16* __restrict__ Vt, int n_base)
{
    __shared__ __align__(16) bf16 smem[17408];    // 34.8 KB: As|Bs then T
    bf16* As = smem;
    bf16* Bs = smem + 8192;
    const int m0 = blockIdx.y * 128, n0 = (blockIdx.x + n_base) * 128;
    f32x4 acc[4][4] = {};
    gemm_core(xb + (long)m0 * DIN, DIN, Wt + (long)n0 * DIN, DIN, DIN / 64, As, Bs, acc);

    const int tid = threadIdx.x;
    const int lane = tid & 63, wave = tid >> 6;
    const int wm = (wave >> 1) * 64, wn = (wave & 1) * 64;
    const int r = lane & 15, qd = lane >> 4;

    if (n0 < 2048) {                               // Q|K: direct store
#pragma unroll
        for (int mi = 0; mi < 4; ++mi)
#pragma unroll
            for (int ni = 0; ni < 4; ++ni)
#pragma unroll
                for (int j = 0; j < 4; ++j) {
                    int row = m0 + wm + mi * 16 + qd * 4 + j;
                    int col = n0 + wn + ni * 16 + r;
                    QK[(long)row * 2048 + col] = __float2bfloat16(acc[mi][ni][j]);
                }
    } else {                                       // V: transpose via LDS
        const int ld = 136;                        // 16B-aligned row stride
        bf16* T = smem;                            // reuse (post-barrier)
#pragma unroll
        for (int mi = 0; mi < 4; ++mi)
#pragma unroll
            for (int ni = 0; ni < 4; ++ni) {
                pack4 p;
#pragma unroll
                for (int j = 0; j < 4; ++j) p.h[j] = __float2bfloat16(acc[mi][ni][j]);
                int d_l = wn + ni * 16 + r;
                int s_l = wm + mi * 16 + qd * 4;
                *(uint2*)&T[d_l * ld + s_l] = p.u2;
            }
        __syncthreads();
        const int n0v = n0 - 2048;
        const int bb = m0 >> 11;                   // batch index
        const int s0 = m0 & 2047;                  // seq offset within batch
        bf16* Ob = Vt + (long)bb * DOUT * SEQ + s0;
#pragma unroll
        for (int p = 0; p < 8; ++p) {
            int l = tid + p * 256;                 // 0..2047
            int d = l >> 4, s8 = (l & 15) * 8;
            bf16x8 vv = *(const bf16x8*)&T[d * ld + s8];
            *(bf16x8*)&Ob[(long)(n0v + d) * SEQ + s8] = vv;
        }
    }
}

// ---------------- scores + exp + row-sum (XCD batch-affinity) ----------------
// bid%8 -> XCD (hw round-robin). Batch b owns XCDs {2b, 2b+1}: the batch's
// 4 MB K-panel + hot Q-tiles become L2-resident per XCD instead of being
// re-fetched from L3/HBM by blocks scattered over all 8 XCDs.
// bid = 8*slot + 2*b + which; t = slot + 68*which covers 136 tiles/batch.

__global__ __launch_bounds__(256, 3)
void k_gemm_scores(const bf16* __restrict__ QK, bf16* __restrict__ P,
                   float* __restrict__ rowSum)
{
    const int bid = blockIdx.x;
    const int lane8 = bid & 7;
    const int b = lane8 >> 1;
    const int t = (bid >> 3) + 68 * (lane8 & 1);   // 0..135
    int rem = t;
    int qt = 15;
    while (rem > qt) { rem -= (qt + 1); --qt; }
    const int kt = rem;

    __shared__ __align__(16) bf16 smem[17408];     // As|Bs then bounce tile
    bf16* As = smem;
    bf16* Bs = smem + 8192;
    const bf16* A  = QK + (long)b * SEQ * 2048;
    const bf16* Bt = A + 1024;
    f32x4 acc[4][4] = {};
    gemm_core(A + (long)qt * 128 * 2048, 2048, Bt + (long)kt * 128 * 2048, 2048,
              DIN / 64, As, Bs, acc);

    bf16* Pb = P + (long)b * SEQ * SEQ;
    float* RS = rowSum + b * SEQ;
    const int tid = threadIdx.x;
    const int lane = tid & 63, wave = tid >> 6;
    const int wm = (wave >> 1) * 64, wn = (wave & 1) * 64;
    const int r = lane & 15, qd = lane >> 4;

    const int ld = 136;                            // bounce-tile stride
    bf16* T = smem;                                // reuse (post-barrier)

    float rp[4][4];
#pragma unroll
    for (int mi = 0; mi < 4; ++mi)
#pragma unroll
        for (int j = 0; j < 4; ++j) rp[mi][j] = 0.f;

#pragma unroll
    for (int mi = 0; mi < 4; ++mi)
#pragma unroll
        for (int ni = 0; ni < 4; ++ni)
#pragma unroll
            for (int j = 0; j < 4; ++j) {
                int row_l = wm + mi * 16 + qd * 4 + j;
                int col_l = wn + ni * 16 + r;
                int row = qt * 128 + row_l;
                int col = kt * 128 + col_l;
                float e = (col > row) ? 0.f : __expf(acc[mi][ni][j] * 0.03125f);
                rp[mi][j] += e;
                T[row_l * ld + col_l] = __float2bfloat16(e);
            }
#pragma unroll
    for (int d = 1; d < 16; d <<= 1)
#pragma unroll
        for (int mi = 0; mi < 4; ++mi)
#pragma unroll
            for (int j = 0; j < 4; ++j)
                rp[mi][j] += __shfl_xor(rp[mi][j], d, 64);
    if (r == 0) {
#pragma unroll
        for (int mi = 0; mi < 4; ++mi)
#pragma unroll
            for (int j = 0; j < 4; ++j) {
                int row = qt * 128 + wm + mi * 16 + qd * 4 + j;
                atomicAdd(&RS[row], rp[mi][j]);
            }
    }
    __syncthreads();
    // bulk coalesced P store: 128x128 tile, b128 per thread x8
#pragma unroll
    for (int p = 0; p < 8; ++p) {
        int l = tid + p * 256;                     // 0..2047
        int row_l = l >> 4, c8 = (l & 15) * 8;
        bf16x8 vv = *(const bf16x8*)&T[row_l * ld + c8];
        *(bf16x8*)&Pb[(long)(qt * 128 + row_l) * SEQ + kt * 128 + c8] = vv;
    }
}

// ---------------- PV: O = (P @ V) / rowSum (XCD batch-affinity) ----------------
// Batch b -> XCDs {2b, 2b+1} (nt parity split: each XCD reuses a 2 MB
// V-half from L2). Within each XCD, per-CU complement pairing: the j-th and
// (j+32)-th blocks on a CU sum to nk=34 -> flat per-CU load.

__global__ __launch_bounds__(256, 3)
void k_gemm_pv(const bf16* __restrict__ P, const bf16* __restrict__ Vt,
               const float* __restrict__ rowSum, float* __restrict__ O)
{
    const int bid = blockIdx.x;                    // 0..511
    const int lane8 = bid & 7;
    const int b   = lane8 >> 1;
    const int par = lane8 & 1;
    const int j   = bid >> 3;                      // 0..63
    int qt, nt;
    if (j < 32) { qt = 15 - (j >> 2); nt = ((j & 3) << 1) + par; }
    else        { int jj = j - 32; qt = jj >> 2; nt = ((jj & 3) << 1) + par; }

    __shared__ __align__(16) bf16 As[128 * 64];
    __shared__ __align__(16) bf16 Bs[128 * 64];
    const bf16* A  = P + (long)b * SEQ * SEQ + (long)qt * 128 * SEQ;
    const bf16* Bt = Vt + (long)b * DOUT * SEQ;
    const int nk = (qt + 1) * 2;                   // K up to (qt+1)*128, BK=64
    f32x4 acc[4][4] = {};
    gemm_core(A, SEQ, Bt + (long)nt * 128 * SEQ, SEQ, nk, As, Bs, acc);

    float* Ob = O + (long)b * SEQ * DOUT;
    const float* RS = rowSum + b * SEQ;
    const int lane = threadIdx.x & 63, wave = threadIdx.x >> 6;
    const int wm = (wave >> 1) * 64, wn = (wave & 1) * 64;
    const int r = lane & 15, qd = lane >> 4;
#pragma unroll
    for (int mi = 0; mi < 4; ++mi)
#pragma unroll
        for (int j2 = 0; j2 < 4; ++j2) {
            int row = qt * 128 + wm + mi * 16 + qd * 4 + j2;
            float inv = 1.0f / RS[row];
#pragma unroll
            for (int ni = 0; ni < 4; ++ni) {
                int col = nt * 128 + wn + ni * 16 + r;
                Ob[(long)row * DOUT + col] = acc[mi][ni][j2] * inv;
            }
        }
}

// ---------------- launch ----------------

extern "C" void kernel_launch(void* const* d_in, const int* in_sizes, int n_in,
                              void* d_out, int out_size, void* d_ws, size_t ws_size,
                              hipStream_t stream)
{
    const float* x  = (const float*)d_in[0];
    const float* Wq = (const float*)d_in[1];
    const float* Wk = (const float*)d_in[2];
    const float* Wv = (const float*)d_in[3];
    float* out = (float*)d_out;

    char* ws = (char*)d_ws;
    bf16*  xb = (bf16*)(ws);                        // 16 MiB
    bf16*  Wt = (bf16*)(ws + 16777216);             //  6 MiB
    bf16*  QK = (bf16*)(ws + 23068672);             // 32 MiB  [row][2048] = Q|K
    bf16*  Vt = (bf16*)(ws + 56623104);             // 16 MiB  [b][d][s]
    bf16*  P  = (bf16*)(ws + 73400320);             // 32 MiB
    float* RS = (float*)(ws + 106954752);           // 32 KiB  (total ~102 MiB)

    k_prep<<<dim3(8192 + 768 + 8), 256, 0, stream>>>(x, Wq, Wk, Wv, xb, Wt, RS);
    k_gemm_qkv<<<dim3(8, 64), 256, 0, stream>>>(xb, Wt, QK, Vt, 0);
    k_gemm_qkv<<<dim3(8, 64), 256, 0, stream>>>(xb, Wt, QK, Vt, 8);
    k_gemm_qkv<<<dim3(8, 64), 256, 0, stream>>>(xb, Wt, QK, Vt, 16);
    k_gemm_scores<<<dim3(544), 256, 0, stream>>>(QK, P, RS);
    k_gemm_pv<<<dim3(512), 256, 0, stream>>>(P, Vt, RS, out);
}

// Round 8
// 211.046 us; speedup vs baseline: 1.1169x; 1.1169x over previous
//
#include <hip/hip_runtime.h>
#include <hip/hip_bf16.h>

#define BATCH 4
#define SEQ   2048
#define DIN   1024
#define DOUT  1024
#define N3    3072
#define MTOT  (BATCH*SEQ)

typedef __hip_bfloat16 bf16;
typedef __attribute__((ext_vector_type(8))) short bf16x8;
typedef __attribute__((ext_vector_type(4))) float f32x4;

#define MFMA(a,b,c) __builtin_amdgcn_mfma_f32_16x16x32_bf16(a,b,c,0,0,0)

union pack4 { bf16 h[4]; uint2 u2; };
union pack8 { bf16 h[8]; bf16x8 v; };

// async 16B global->LDS (DMA, no VGPR round-trip)
__device__ __forceinline__ void gl16(const bf16* g, bf16* l)
{
    __builtin_amdgcn_global_load_lds(
        (const __attribute__((address_space(1))) void*)g,
        (__attribute__((address_space(3))) void*)l, 16, 0, 0);
}

// ---------------- fused conversions (+ RS zero-fill) ----------------

__global__ __launch_bounds__(256)
void k_prep(const float* __restrict__ x, const float* __restrict__ Wq,
            const float* __restrict__ Wk, const float* __restrict__ Wv,
            bf16* __restrict__ xb, bf16* __restrict__ Wt,
            float* __restrict__ RS)
{
    __shared__ bf16 t[64][68];
    const int bid = blockIdx.x;
    if (bid < 8192) {
        long i = ((long)bid * 256 + threadIdx.x) * 4;
        float4 v = *(const float4*)(x + i);
        pack4 o;
        o.h[0] = __float2bfloat16(v.x);
        o.h[1] = __float2bfloat16(v.y);
        o.h[2] = __float2bfloat16(v.z);
        o.h[3] = __float2bfloat16(v.w);
        *(uint2*)(xb + i) = o.u2;
        return;
    }
    if (bid >= 8960) {                         // RS zero-fill (8192 floats)
        int i = (bid - 8960) * 1024 + threadIdx.x * 4;
        *(float4*)(RS + i) = make_float4(0.f, 0.f, 0.f, 0.f);
        return;
    }
    const int idx = bid - 8192;                // 0..767
    const int mat = idx >> 8;
    const int rem = idx & 255;
    const int k0 = (rem >> 4) * 64, n0 = (rem & 15) * 64;
    const float* W = (mat == 0) ? Wq : ((mat == 1) ? Wk : Wv);
#pragma unroll
    for (int p = 0; p < 4; ++p) {
        int kr = p * 16 + (threadIdx.x >> 4);
        int c4 = (threadIdx.x & 15) * 4;
        float4 v = *(const float4*)&W[(long)(k0 + kr) * DOUT + n0 + c4];
        t[c4 + 0][kr] = __float2bfloat16(v.x);
        t[c4 + 1][kr] = __float2bfloat16(v.y);
        t[c4 + 2][kr] = __float2bfloat16(v.z);
        t[c4 + 3][kr] = __float2bfloat16(v.w);
    }
    __syncthreads();
    bf16* O = Wt + (long)mat * DIN * DOUT;
#pragma unroll
    for (int i = 0; i < 2; ++i) {
        int l = threadIdx.x + i * 256;
        int n = l >> 3, c8 = (l & 7) * 8;
        pack8 o;
#pragma unroll
        for (int j = 0; j < 8; ++j) o.h[j] = t[n][c8 + j];
        *(bf16x8*)&O[(long)(n0 + n) * DIN + k0 + c8] = o.v;
    }
}

// ---------------- shared GEMM core, BK=64 (round-0 verified) ----------------
// 128x128 tile, BK=64 (32 MFMA per barrier pair), 4 waves 2x2, each wave
// 64x64 via 4x4 mfma 16x16x32 over 2 k-steps. XOR-swizzled LDS (0 conflicts).
// DIAG=1 (scores diagonal tiles only): skip fragment reads + MFMA for
// subtiles that are FULLY causally masked (their outputs are overwritten
// with 0 in the epilogue regardless, so numerics are bit-identical):
// wave (wm=0,wn=64) -> entire wave's outputs have col>=64>row_max=63;
// wn==wm waves -> subtiles with ni>mi. ~44% of diag-block MFMAs removed.

template<int DIAG>
__device__ __forceinline__ void gemm_core(
    const bf16* __restrict__ Ab, long lda,
    const bf16* __restrict__ Bb, long ldb,
    int nk, bf16* __restrict__ As, bf16* __restrict__ Bs,
    f32x4 acc[4][4])
{
    const int tid  = threadIdx.x;
    const int lane = tid & 63;
    const int wave = tid >> 6;
    const int wm = (wave >> 1) * 64;
    const int wn = (wave & 1) * 64;
    const int r  = lane & 15;
    const int qd = lane >> 4;

    const bool skipWave = DIAG && (wn > wm);      // fully-masked wave
    const bool sameOff  = DIAG && (wn == wm);

    const int row0 = tid >> 3;                    // 0..31
    const int c    = (tid & 7) ^ (row0 & 7);      // swizzled source chunk
    const long aoff = (long)row0 * lda + c * 8;
    const long boff = (long)row0 * ldb + c * 8;
    const long astep = 32 * lda, bstep = 32 * ldb;
    bf16* dA = &As[tid * 8];
    bf16* dB = &Bs[tid * 8];

    for (int kk = 0; kk < nk; ++kk) {
        const bf16* A = Ab + kk * 64 + aoff;
        const bf16* B = Bb + kk * 64 + boff;
#pragma unroll
        for (int i = 0; i < 4; ++i) {
            gl16(A + i * astep, dA + i * 2048);
            gl16(B + i * bstep, dB + i * 2048);
        }
        __syncthreads();                           // drains vmcnt
        if (!skipWave) {
#pragma unroll
            for (int ks = 0; ks < 2; ++ks) {
                const int slot = ((ks * 4 + qd) ^ (r & 7)) * 8;
                bf16x8 af[4], bv[4];
#pragma unroll
                for (int mi = 0; mi < 4; ++mi)
                    af[mi] = *(const bf16x8*)&As[(wm + mi * 16 + r) * 64 + slot];
#pragma unroll
                for (int ni = 0; ni < 4; ++ni)
                    bv[ni] = *(const bf16x8*)&Bs[(wn + ni * 16 + r) * 64 + slot];
#pragma unroll
                for (int mi = 0; mi < 4; ++mi)
#pragma unroll
                    for (int ni = 0; ni < 4; ++ni) {
                        if (sameOff && ni > mi) continue;   // fully masked
                        acc[mi][ni] = MFMA(af[mi], bv[ni], acc[mi][ni]);
                    }
            }
        }
        __syncthreads();
    }
}

// ---------------- QKV projection (round-0 verified) ----------------

__global__ __launch_bounds__(256)
void k_gemm_qkv(const bf16* __restrict__ xb, const bf16* __restrict__ Wt,
                bf16* __restrict__ QK, bf16* __restrict__ Vt)
{
    __shared__ __align__(16) bf16 smem[17408];    // 34.8 KB: As|Bs then T
    bf16* As = smem;
    bf16* Bs = smem + 8192;
    const int m0 = blockIdx.y * 128, n0 = blockIdx.x * 128;
    f32x4 acc[4][4] = {};
    gemm_core<0>(xb + (long)m0 * DIN, DIN, Wt + (long)n0 * DIN, DIN, DIN / 64, As, Bs, acc);

    const int tid = threadIdx.x;
    const int lane = tid & 63, wave = tid >> 6;
    const int wm = (wave >> 1) * 64, wn = (wave & 1) * 64;
    const int r = lane & 15, qd = lane >> 4;

    if (n0 < 2048) {                               // Q|K: direct store
#pragma unroll
        for (int mi = 0; mi < 4; ++mi)
#pragma unroll
            for (int ni = 0; ni < 4; ++ni)
#pragma unroll
                for (int j = 0; j < 4; ++j) {
                    int row = m0 + wm + mi * 16 + qd * 4 + j;
                    int col = n0 + wn + ni * 16 + r;
                    QK[(long)row * 2048 + col] = __float2bfloat16(acc[mi][ni][j]);
                }
    } else {                                       // V: transpose via LDS
        const int ld = 136;                        // 16B-aligned row stride
        bf16* T = smem;                            // reuse (post-barrier)
#pragma unroll
        for (int mi = 0; mi < 4; ++mi)
#pragma unroll
            for (int ni = 0; ni < 4; ++ni) {
                pack4 p;
#pragma unroll
                for (int j = 0; j < 4; ++j) p.h[j] = __float2bfloat16(acc[mi][ni][j]);
                int d_l = wn + ni * 16 + r;
                int s_l = wm + mi * 16 + qd * 4;
                *(uint2*)&T[d_l * ld + s_l] = p.u2;
            }
        __syncthreads();
        const int n0v = n0 - 2048;
        const int bb = m0 >> 11;                   // batch index
        const int s0 = m0 & 2047;                  // seq offset within batch
        bf16* Ob = Vt + (long)bb * DOUT * SEQ + s0;
#pragma unroll
        for (int p = 0; p < 8; ++p) {
            int l = tid + p * 256;                 // 0..2047
            int d = l >> 4, s8 = (l & 15) * 8;
            bf16x8 vv = *(const bf16x8*)&T[d * ld + s8];
            *(bf16x8*)&Ob[(long)(n0v + d) * SEQ + s8] = vv;
        }
    }
}

// ---------------- scores + exp + row-sum ----------------
// 544 = 480 off-diagonal tiles (bid 0..479, qt-descending, batches
// interleaved) + 64 diagonal tiles LAST (bid 480..543) so the 3rd-per-CU
// straggler blocks get the ~44%-cheaper DIAG-skip tiles.
// P written via LDS bounce -> b128 coalesced stores.

__global__ __launch_bounds__(256, 3)
void k_gemm_scores(const bf16* __restrict__ QK, bf16* __restrict__ P,
                   float* __restrict__ rowSum)
{
    const int bid = blockIdx.x;
    int b, qt, kt;
    if (bid < 480) {                               // off-diagonal
        b = bid & 3;
        int u = bid >> 2;                          // 0..119
        qt = 15;
        while (u >= qt) { u -= qt; --qt; }         // qt has qt off-diag tiles
        kt = u;                                    // kt < qt
    } else {                                       // diagonal, last
        int i = bid - 480;                         // 0..63
        b = i & 3;
        qt = kt = i >> 2;
    }

    __shared__ __align__(16) bf16 smem[17408];     // As|Bs then bounce tile
    bf16* As = smem;
    bf16* Bs = smem + 8192;
    const bf16* A  = QK + (long)b * SEQ * 2048;
    const bf16* Bt = A + 1024;
    f32x4 acc[4][4] = {};
    if (bid < 480)
        gemm_core<0>(A + (long)qt * 128 * 2048, 2048, Bt + (long)kt * 128 * 2048,
                     2048, DIN / 64, As, Bs, acc);
    else
        gemm_core<1>(A + (long)qt * 128 * 2048, 2048, Bt + (long)kt * 128 * 2048,
                     2048, DIN / 64, As, Bs, acc);

    bf16* Pb = P + (long)b * SEQ * SEQ;
    float* RS = rowSum + b * SEQ;
    const int tid = threadIdx.x;
    const int lane = tid & 63, wave = tid >> 6;
    const int wm = (wave >> 1) * 64, wn = (wave & 1) * 64;
    const int r = lane & 15, qd = lane >> 4;

    const int ld = 136;                            // bounce-tile stride
    bf16* T = smem;                                // reuse (post-barrier)

    float rp[4][4];
#pragma unroll
    for (int mi = 0; mi < 4; ++mi)
#pragma unroll
        for (int j = 0; j < 4; ++j) rp[mi][j] = 0.f;

#pragma unroll
    for (int mi = 0; mi < 4; ++mi)
#pragma unroll
        for (int ni = 0; ni < 4; ++ni)
#pragma unroll
            for (int j = 0; j < 4; ++j) {
                int row_l = wm + mi * 16 + qd * 4 + j;
                int col_l = wn + ni * 16 + r;
                int row = qt * 128 + row_l;
                int col = kt * 128 + col_l;
                float e = (col > row) ? 0.f : __expf(acc[mi][ni][j] * 0.03125f);
                rp[mi][j] += e;
                T[row_l * ld + col_l] = __float2bfloat16(e);
            }
#pragma unroll
    for (int d = 1; d < 16; d <<= 1)
#pragma unroll
        for (int mi = 0; mi < 4; ++mi)
#pragma unroll
            for (int j = 0; j < 4; ++j)
                rp[mi][j] += __shfl_xor(rp[mi][j], d, 64);
    if (r == 0) {
#pragma unroll
        for (int mi = 0; mi < 4; ++mi)
#pragma unroll
            for (int j = 0; j < 4; ++j) {
                int row = qt * 128 + wm + mi * 16 + qd * 4 + j;
                atomicAdd(&RS[row], rp[mi][j]);
            }
    }
    __syncthreads();
    // bulk coalesced P store: 128x128 tile, b128 per thread x8
#pragma unroll
    for (int p = 0; p < 8; ++p) {
        int l = tid + p * 256;                     // 0..2047
        int row_l = l >> 4, c8 = (l & 15) * 8;
        bf16x8 vv = *(const bf16x8*)&T[row_l * ld + c8];
        *(bf16x8*)&Pb[(long)(qt * 128 + row_l) * SEQ + kt * 128 + c8] = vv;
    }
}

// ---------------- PV: O = (P @ V) / rowSum (round-6 verified) ----------------
// Complement-pair ordering: 512 blocks = 2/CU all co-resident. First 256
// blocks carry the heavy half (qt 15..8), second 256 the light half ordered
// qt 0..7; CU c gets blocks {c, c+256}: nk sum = 34 for every CU.

__global__ __launch_bounds__(256, 3)
void k_gemm_pv(const bf16* __restrict__ P, const bf16* __restrict__ Vt,
               const float* __restrict__ rowSum, float* __restrict__ O)
{
    const int bid = blockIdx.x;                    // 0..511
    const int h   = bid & 255;
    const int qt  = (bid < 256) ? (15 - (h >> 5)) : (h >> 5);
    const int b   = (h >> 3) & 3;
    const int nt  = h & 7;
    __shared__ __align__(16) bf16 As[128 * 64];
    __shared__ __align__(16) bf16 Bs[128 * 64];
    const bf16* A  = P + (long)b * SEQ * SEQ + (long)qt * 128 * SEQ;
    const bf16* Bt = Vt + (long)b * DOUT * SEQ;
    const int nk = (qt + 1) * 2;                   // K up to (qt+1)*128, BK=64
    f32x4 acc[4][4] = {};
    gemm_core<0>(A, SEQ, Bt + (long)nt * 128 * SEQ, SEQ, nk, As, Bs, acc);

    float* Ob = O + (long)b * SEQ * DOUT;
    const float* RS = rowSum + b * SEQ;
    const int lane = threadIdx.x & 63, wave = threadIdx.x >> 6;
    const int wm = (wave >> 1) * 64, wn = (wave & 1) * 64;
    const int r = lane & 15, qd = lane >> 4;
#pragma unroll
    for (int mi = 0; mi < 4; ++mi)
#pragma unroll
        for (int j = 0; j < 4; ++j) {
            int row = qt * 128 + wm + mi * 16 + qd * 4 + j;
            float inv = 1.0f / RS[row];
#pragma unroll
            for (int ni = 0; ni < 4; ++ni) {
                int col = nt * 128 + wn + ni * 16 + r;
                Ob[(long)row * DOUT + col] = acc[mi][ni][j] * inv;
            }
        }
}

// ---------------- launch ----------------

extern "C" void kernel_launch(void* const* d_in, const int* in_sizes, int n_in,
                              void* d_out, int out_size, void* d_ws, size_t ws_size,
                              hipStream_t stream)
{
    const float* x  = (const float*)d_in[0];
    const float* Wq = (const float*)d_in[1];
    const float* Wk = (const float*)d_in[2];
    const float* Wv = (const float*)d_in[3];
    float* out = (float*)d_out;

    char* ws = (char*)d_ws;
    bf16*  xb = (bf16*)(ws);                        // 16 MiB
    bf16*  Wt = (bf16*)(ws + 16777216);             //  6 MiB
    bf16*  QK = (bf16*)(ws + 23068672);             // 32 MiB  [row][2048] = Q|K
    bf16*  Vt = (bf16*)(ws + 56623104);             // 16 MiB  [b][d][s]
    bf16*  P  = (bf16*)(ws + 73400320);             // 32 MiB
    float* RS = (float*)(ws + 106954752);           // 32 KiB  (total ~102 MiB)

    k_prep<<<dim3(8192 + 768 + 8), 256, 0, stream>>>(x, Wq, Wk, Wv, xb, Wt, RS);
    k_gemm_qkv<<<dim3(N3 / 128, MTOT / 128), 256, 0, stream>>>(xb, Wt, QK, Vt);
    k_gemm_scores<<<dim3(544), 256, 0, stream>>>(QK, P, RS);
    k_gemm_pv<<<dim3(512), 256, 0, stream>>>(P, Vt, RS, out);
}